// Round 9
// baseline (9915.932 us; speedup 1.0000x reference)
//
#include <hip/hip_runtime.h>
#include <cmath>

#define BATCH 32
#define SEQ   2048
#define EMB   512
#define NOUT  256
#define PS    16
#define KW    16
#define FG    32    // (b,n) pairs per conv block
#define JTOT  8192  // K*E flat contraction length, j = k*512 + i (i fastest)
#define KCB   288   // Eigen threaded gebp kc: min((32K-384)/112,320)=289 -> 288
#define KCL   288   // linear dot panel: 512 = 288 + 224

// XLA EmitFastTanh / Eigen ptanh_float: rational approx, f32, FMA Horner.
__device__ __forceinline__ float xla_tanhf(float x) {
#pragma clang fp contract(off)
    float ax = fabsf(x);
    float xc = x;
    if (xc < -7.90531110763549805f) xc = -7.90531110763549805f;
    if (xc >  7.90531110763549805f) xc =  7.90531110763549805f;
    float x2 = xc * xc;
    float p = __builtin_fmaf(x2, -2.76076847742355e-16f, 2.00018790482477e-13f);
    p = __builtin_fmaf(x2, p, -8.60467152213735e-11f);
    p = __builtin_fmaf(x2, p,  5.12229709037114e-08f);
    p = __builtin_fmaf(x2, p,  1.48572235717979e-05f);
    p = __builtin_fmaf(x2, p,  6.37261928875436e-04f);
    p = __builtin_fmaf(x2, p,  4.89352455891786e-03f);
    float num = xc * p;
    float q = __builtin_fmaf(x2, 1.19825839466702e-06f, 1.18534705686654e-04f);
    q = __builtin_fmaf(x2, q, 2.26843463243900e-03f);
    q = __builtin_fmaf(x2, q, 4.89352518554385e-03f);
    float r = num / q;
    return (ax < 0.0004f) ? x : r;
}

// K1: wT[j][o] = conv_w[o][i][k],  j = k*512 + i  (XLA/Eigen im2col order:
// channel fastest within patch), lane-coalesced in o.
__global__ __launch_bounds__(256) void k_transpose_w(const float* __restrict__ w,
                                                     float* __restrict__ wT) {
    int t = blockIdx.x * 256 + threadIdx.x;   // t = j*512 + o
    int o = t & 511;
    int i = (t >> 9) & 511;
    int k = t >> 18;
    wT[t] = w[(size_t)o * 8192 + i * 16 + k];
}

// K2: conv1d as Eigen-threaded im2col gebp replica:
//   j = k*512 + i ; panels of kc=288 (28x288 + 128), each panel a sequential
//   FMA chain per output, panels left-folded into C (C=p0; C+=p1; ...).
//   y = C + conv_b[o] afterwards.
__global__ __launch_bounds__(512) void k_conv(const float* __restrict__ x,
                                              const float* __restrict__ wT,
                                              const float* __restrict__ cb,
                                              float* __restrict__ y) {
#pragma clang fp contract(off)
    int g = blockIdx.x;          // 0..255
    int o = threadIdx.x;         // 0..511
    int b  = g >> 3;
    int n0 = (g & 7) * FG;

    float ysum[FG];
#pragma unroll
    for (int f = 0; f < FG; ++f) ysum[f] = 0.0f;

    const float* xb = x + (size_t)b * SEQ * EMB;

    for (int j0 = 0; j0 < JTOT; j0 += KCB) {
        int j1 = j0 + KCB;
        if (j1 > JTOT) j1 = JTOT;      // last panel = 128

        float pk[FG];
#pragma unroll
        for (int f = 0; f < FG; ++f) pk[f] = 0.0f;

        for (int j = j0; j < j1; ++j) {
            int k = j >> 9;            // k outer
            int i = j & 511;           // i (channel) inner
            float wv = wT[((size_t)j << 9) + o];
            int sbase = (n0 << 3) + k - 4;
#pragma unroll
            for (int f = 0; f < FG; ++f) {
                int s = sbase + (f << 3);
                // OOB taps: xv=0 -> fma(0,w,p)==p exactly == zero-pad term.
                float xv = (s >= 0 && s < SEQ) ? xb[((size_t)s << 9) + i] : 0.0f;
                pk[f] = __builtin_fmaf(xv, wv, pk[f]);
            }
        }
#pragma unroll
        for (int f = 0; f < FG; ++f) ysum[f] = ysum[f] + pk[f];  // panel left-fold
    }

#pragma unroll
    for (int f = 0; f < FG; ++f) {
        int bn = (b << 8) + n0 + f;
        y[((size_t)bn << 9) + o] = ysum[f] + cb[o];   // bias after full gemm
    }
}

// K3: per (b,n): off = relu(y) @ lin_w.T + lin_b with Eigen kc=288 panel split
// (512 = 288 + 224), then decode op-for-op in f32 (contract off), XLA tanh,
// jax-f32 linspace t (t = p * f32(1/15)).
__global__ __launch_bounds__(256) void k_decode(const float* __restrict__ y,
                                               const float* __restrict__ lw,
                                               const float* __restrict__ lb,
                                               const float* __restrict__ wb,
                                               int* __restrict__ idx) {
#pragma clang fp contract(off)
    int bn = blockIdx.x * 256 + threadIdx.x;   // 0..8191
    if (bn >= BATCH * NOUT) return;
    const float* yy = y + ((size_t)bn << 9);

    float s0, s1;
    {
        float p0 = 0.0f, p1 = 0.0f;
        for (int e = 0; e < KCL; ++e) {
            float v = yy[e];
            float r = v > 0.0f ? v : 0.0f;
            p0 = __builtin_fmaf(r, lw[e],       p0);
            p1 = __builtin_fmaf(r, lw[EMB + e], p1);
        }
        s0 = p0; s1 = p1;                  // panel 0 stores (beta=0)
    }
    {
        float p0 = 0.0f, p1 = 0.0f;
        for (int e = KCL; e < EMB; ++e) {
            float v = yy[e];
            float r = v > 0.0f ? v : 0.0f;
            p0 = __builtin_fmaf(r, lw[e],       p0);
            p1 = __builtin_fmaf(r, lw[EMB + e], p1);
        }
        s0 = s0 + p0; s1 = s1 + p1;        // panel 1 accumulates
    }
    float off0 = s0 + lb[0];
    float off1 = s1 + lb[1];

    int n = bn & (NOUT - 1);
    float anchor = (0.5f + (float)n) / 256.0f;        // exact in f32
    float dx  = xla_tanhf(off0) * 0.00390625f;        // * poi (2^-8, exact)
    float a1  = off1 + wb[0];
    float tww = xla_tanhf(a1);
    float rwv = tww > 0.0f ? tww : 0.0f;
    float dwv = rwv * 0.00390625f;
    float adx = anchor + dx;                          // left-assoc like jnp
    float x0 = adx - dwv; x0 = x0 < 0.0f ? 0.0f : (x0 > 1.0f ? 1.0f : x0);
    float x1 = adx + dwv; x1 = x1 < 0.0f ? 0.0f : (x1 > 1.0f ? 1.0f : x1);

    const float delta = 1.0f / 15.0f;                 // f32 0.06666667
#pragma unroll
    for (int p = 0; p < PS; ++p) {
        float t  = (float)p * delta;                  // jax linspace: iota*delta, f32
        float om = 1.0f - t;
        float gs = x0 * om + x1 * t;                  // mul,mul,add — contract off
        float gxn = 2.0f * gs - 1.0f;
        float gp1 = gxn + 1.0f;
        float ixx = (gp1 * 2048.0f - 1.0f) * 0.5f;
        float rr = rintf(ixx);                        // round half-even
        int id = (int)rr;
        id = id < 0 ? 0 : (id > SEQ - 1 ? SEQ - 1 : id);
        idx[bn * PS + p] = id;
    }
}

// K4: out[b][n][p][:] = x[b][idx[b,n,p]][:]   (exact f32 row copy, 2048 B)
__global__ __launch_bounds__(128) void k_gather(const float* __restrict__ x,
                                                const int* __restrict__ idx,
                                                float* __restrict__ out) {
    int g = blockIdx.x;                 // (b*256+n)*16+p, 131072 blocks
    int b = g >> 12;
    int sidx = idx[g];
    const float4* src = (const float4*)(x + (((size_t)b * SEQ + sidx) << 9));
    float4* dst = (float4*)(out + ((size_t)g << 9));
    dst[threadIdx.x] = src[threadIdx.x];
}

extern "C" void kernel_launch(void* const* d_in, const int* in_sizes, int n_in,
                              void* d_out, int out_size, void* d_ws, size_t ws_size,
                              hipStream_t stream) {
    const float* x      = (const float*)d_in[0];
    const float* conv_w = (const float*)d_in[1];
    const float* conv_b = (const float*)d_in[2];
    const float* lin_w  = (const float*)d_in[3];
    const float* lin_b  = (const float*)d_in[4];
    const float* wbias  = (const float*)d_in[5];
    float* out = (float*)d_out;

    // Scratch inside d_out (268 MB f32): wT [0,16.8MB), y [16.8,33.6MB).
    // Both consumed by k_decode before k_gather overwrites d_out.
    // idx (512 KB) in d_ws.
    float* wT  = (float*)d_out;
    float* y   = (float*)((char*)d_out + (size_t)16777216);
    int*   idx = (int*)d_ws;

    hipLaunchKernelGGL(k_transpose_w, dim3(16384), dim3(256), 0, stream, conv_w, wT);
    hipLaunchKernelGGL(k_conv,        dim3(256),   dim3(512), 0, stream, x, wT, conv_b, y);
    hipLaunchKernelGGL(k_decode,      dim3(32),    dim3(256), 0, stream, y, lin_w, lin_b, wbias, idx);
    hipLaunchKernelGGL(k_gather,      dim3(BATCH * NOUT * PS), dim3(128), 0, stream, x, idx, out);
}

// Round 10
// 1007.498 us; speedup vs baseline: 9.8421x; 9.8421x over previous
//
#include <hip/hip_runtime.h>
#include <cmath>

#define BATCH 32
#define SEQ   2048
#define EMB   512
#define NOUT  256
#define PS    16
#define KW    16
#define JTOT  8192  // K*E flat contraction length, j = k*512 + i (i fastest)
#define KCL   288   // Eigen threaded gebp kc (linear dot: 512 = 288 + 224)

// GEMM tiling for k_conv: M=bn (8192), N=o (512), K=j (8192)
#define MB 64       // bn-tile
#define NB 128      // o-tile
#define KS 32       // j-tile; 288 = 9*KS, tail 128 = 4*KS -> panel folds align

// XLA EmitFastTanh / Eigen ptanh_float: rational approx, f32, FMA Horner.
__device__ __forceinline__ float xla_tanhf(float x) {
#pragma clang fp contract(off)
    float ax = fabsf(x);
    float xc = x;
    if (xc < -7.90531110763549805f) xc = -7.90531110763549805f;
    if (xc >  7.90531110763549805f) xc =  7.90531110763549805f;
    float x2 = xc * xc;
    float p = __builtin_fmaf(x2, -2.76076847742355e-16f, 2.00018790482477e-13f);
    p = __builtin_fmaf(x2, p, -8.60467152213735e-11f);
    p = __builtin_fmaf(x2, p,  5.12229709037114e-08f);
    p = __builtin_fmaf(x2, p,  1.48572235717979e-05f);
    p = __builtin_fmaf(x2, p,  6.37261928875436e-04f);
    p = __builtin_fmaf(x2, p,  4.89352455891786e-03f);
    float num = xc * p;
    float q = __builtin_fmaf(x2, 1.19825839466702e-06f, 1.18534705686654e-04f);
    q = __builtin_fmaf(x2, q, 2.26843463243900e-03f);
    q = __builtin_fmaf(x2, q, 4.89352518554385e-03f);
    float r = num / q;
    return (ax < 0.0004f) ? x : r;
}

// K1: wT[j][o] = conv_w[o][i][k],  j = k*512 + i  (XLA/Eigen im2col order)
__global__ __launch_bounds__(256) void k_transpose_w(const float* __restrict__ w,
                                                     float* __restrict__ wT) {
    int t = blockIdx.x * 256 + threadIdx.x;   // t = j*512 + o
    int o = t & 511;
    int i = (t >> 9) & 511;
    int k = t >> 18;
    wT[t] = w[(size_t)o * 8192 + i * 16 + k];
}

// K2: conv1d as LDS-tiled f32 GEMM, bit-exact Eigen gebp accumulation:
//   per output (bn,o): panels of kc=288 over j (k-major, i-minor), each panel
//   a sequential fmaf chain (pk), panels left-folded into ysum in order.
//   KS=32 divides 288 (9 tiles) and the 128 tail (4 tiles), so folds happen
//   only at tile boundaries: after js%9==8 and after js=255.
__global__ __launch_bounds__(256) void k_conv(const float* __restrict__ x,
                                              const float* __restrict__ wT,
                                              const float* __restrict__ cb,
                                              float* __restrict__ y) {
#pragma clang fp contract(off)
    __shared__ __align__(16) float sA[KS][MB + 4];   // [kk][m], +4 pad
    __shared__ __align__(16) float sB[KS][NB];       // [kk][o']

    int bm  = blockIdx.x;          // 0..127
    int bn0 = bm << 6;
    int b   = bn0 >> 8;            // 64 | 256 -> single b per tile
    int n0  = bn0 & 255;
    int o0  = blockIdx.y << 7;     // 0..3

    int tid = threadIdx.x;
    int tm  = tid & 15;            // 4 m-rows each
    int tn  = tid >> 4;            // 8 o-cols each

    float ys[4][8], pk[4][8];
#pragma unroll
    for (int mi = 0; mi < 4; ++mi)
#pragma unroll
        for (int ni = 0; ni < 8; ++ni) { ys[mi][ni] = 0.0f; pk[mi][ni] = 0.0f; }

    const float* xb = x + (size_t)b * SEQ * EMB;

    for (int js = 0; js < 256; ++js) {
        int k  = js >> 4;              // j = js*32 + kk ; k = j>>9 (const per tile)
        int i0 = (js & 15) << 5;       // i = i0 + kk
        __syncthreads();
        // stage A: sA[kk][m] = x[b][8(n0+m)-4+k][i0+kk]  (0 if OOB; exact no-op)
#pragma unroll
        for (int r = 0; r < 2; ++r) {
            int q  = tid + (r << 8);
            int m  = q >> 3;               // 0..63
            int c4 = (q & 7) << 2;         // kk base 0,4,...,28
            int s  = ((n0 + m) << 3) - 4 + k;
            float4 v = make_float4(0.f, 0.f, 0.f, 0.f);
            if (s >= 0 && s < SEQ)
                v = *(const float4*)(xb + ((size_t)s << 9) + i0 + c4);
            sA[c4 + 0][m] = v.x; sA[c4 + 1][m] = v.y;
            sA[c4 + 2][m] = v.z; sA[c4 + 3][m] = v.w;
        }
        // stage B: sB[kk][o'] = wT[(js*32+kk)*512 + o0+o']  (coalesced both ways)
        {
            const float* wrow = wT + (((size_t)js << 5) << 9) + o0;
#pragma unroll
            for (int r = 0; r < 4; ++r) {
                int q  = tid + (r << 8);
                int kk = q >> 5;           // 0..31
                int o4 = (q & 31) << 2;    // 0,4,...,124
                *(float4*)&sB[kk][o4] = *(const float4*)(wrow + ((size_t)kk << 9) + o4);
            }
        }
        __syncthreads();
        // micro-kernel: pk chains ascend in kk (exact panel order)
#pragma unroll
        for (int kk = 0; kk < KS; ++kk) {
            float4 a  = *(const float4*)&sA[kk][tm << 2];
            float4 b0 = *(const float4*)&sB[kk][tn << 3];
            float4 b1 = *(const float4*)&sB[kk][(tn << 3) + 4];
            float av[4] = {a.x, a.y, a.z, a.w};
            float bv[8] = {b0.x, b0.y, b0.z, b0.w, b1.x, b1.y, b1.z, b1.w};
#pragma unroll
            for (int mi = 0; mi < 4; ++mi)
#pragma unroll
                for (int ni = 0; ni < 8; ++ni)
                    pk[mi][ni] = __builtin_fmaf(av[mi], bv[ni], pk[mi][ni]);
        }
        // panel left-fold (ysum += pk) at kc=288 boundaries and the 128 tail
        if ((js % 9) == 8 || js == 255) {
#pragma unroll
            for (int mi = 0; mi < 4; ++mi)
#pragma unroll
                for (int ni = 0; ni < 8; ++ni) {
                    ys[mi][ni] = ys[mi][ni] + pk[mi][ni];
                    pk[mi][ni] = 0.0f;
                }
        }
    }

    const float* cbp = cb + o0 + (tn << 3);
#pragma unroll
    for (int mi = 0; mi < 4; ++mi) {
        int n = n0 + (tm << 2) + mi;
        float* dst = y + (((size_t)(b << 8) + n) << 9) + o0 + (tn << 3);
#pragma unroll
        for (int ni = 0; ni < 8; ++ni)
            dst[ni] = ys[mi][ni] + cbp[ni];   // bias after full gemm (exact r9 order)
    }
}

// K3: per (b,n): off = relu(y) @ lin_w.T + lin_b with Eigen kc=288 panel split
// (512 = 288 + 224), then decode op-for-op in f32 (contract off), XLA tanh,
// jax-f32 linspace t (t = p * f32(1/15)).
__global__ __launch_bounds__(256) void k_decode(const float* __restrict__ y,
                                               const float* __restrict__ lw,
                                               const float* __restrict__ lb,
                                               const float* __restrict__ wb,
                                               int* __restrict__ idx) {
#pragma clang fp contract(off)
    int bn = blockIdx.x * 256 + threadIdx.x;   // 0..8191
    if (bn >= BATCH * NOUT) return;
    const float* yy = y + ((size_t)bn << 9);

    float s0, s1;
    {
        float p0 = 0.0f, p1 = 0.0f;
        for (int e = 0; e < KCL; ++e) {
            float v = yy[e];
            float r = v > 0.0f ? v : 0.0f;
            p0 = __builtin_fmaf(r, lw[e],       p0);
            p1 = __builtin_fmaf(r, lw[EMB + e], p1);
        }
        s0 = p0; s1 = p1;                  // panel 0 stores (beta=0)
    }
    {
        float p0 = 0.0f, p1 = 0.0f;
        for (int e = KCL; e < EMB; ++e) {
            float v = yy[e];
            float r = v > 0.0f ? v : 0.0f;
            p0 = __builtin_fmaf(r, lw[e],       p0);
            p1 = __builtin_fmaf(r, lw[EMB + e], p1);
        }
        s0 = s0 + p0; s1 = s1 + p1;        // panel 1 accumulates
    }
    float off0 = s0 + lb[0];
    float off1 = s1 + lb[1];

    int n = bn & (NOUT - 1);
    float anchor = (0.5f + (float)n) / 256.0f;        // exact in f32
    float dx  = xla_tanhf(off0) * 0.00390625f;        // * poi (2^-8, exact)
    float a1  = off1 + wb[0];
    float tww = xla_tanhf(a1);
    float rwv = tww > 0.0f ? tww : 0.0f;
    float dwv = rwv * 0.00390625f;
    float adx = anchor + dx;                          // left-assoc like jnp
    float x0 = adx - dwv; x0 = x0 < 0.0f ? 0.0f : (x0 > 1.0f ? 1.0f : x0);
    float x1 = adx + dwv; x1 = x1 < 0.0f ? 0.0f : (x1 > 1.0f ? 1.0f : x1);

    const float delta = 1.0f / 15.0f;                 // f32 0.06666667
#pragma unroll
    for (int p = 0; p < PS; ++p) {
        float t  = (float)p * delta;                  // jax linspace: iota*delta, f32
        float om = 1.0f - t;
        float gs = x0 * om + x1 * t;                  // mul,mul,add — contract off
        float gxn = 2.0f * gs - 1.0f;
        float gp1 = gxn + 1.0f;
        float ixx = (gp1 * 2048.0f - 1.0f) * 0.5f;
        float rr = rintf(ixx);                        // round half-even
        int id = (int)rr;
        id = id < 0 ? 0 : (id > SEQ - 1 ? SEQ - 1 : id);
        idx[bn * PS + p] = id;
    }
}

// K4: out[b][n][p][:] = x[b][idx[b,n,p]][:]   (exact f32 row copy, 2048 B)
__global__ __launch_bounds__(128) void k_gather(const float* __restrict__ x,
                                                const int* __restrict__ idx,
                                                float* __restrict__ out) {
    int g = blockIdx.x;                 // (b*256+n)*16+p, 131072 blocks
    int b = g >> 12;
    int sidx = idx[g];
    const float4* src = (const float4*)(x + (((size_t)b * SEQ + sidx) << 9));
    float4* dst = (float4*)(out + ((size_t)g << 9));
    dst[threadIdx.x] = src[threadIdx.x];
}

extern "C" void kernel_launch(void* const* d_in, const int* in_sizes, int n_in,
                              void* d_out, int out_size, void* d_ws, size_t ws_size,
                              hipStream_t stream) {
    const float* x      = (const float*)d_in[0];
    const float* conv_w = (const float*)d_in[1];
    const float* conv_b = (const float*)d_in[2];
    const float* lin_w  = (const float*)d_in[3];
    const float* lin_b  = (const float*)d_in[4];
    const float* wbias  = (const float*)d_in[5];
    float* out = (float*)d_out;

    // Scratch inside d_out (268 MB f32): wT [0,16.8MB), y [16.8,33.6MB).
    // Both consumed by k_decode before k_gather overwrites d_out.
    // idx (512 KB) in d_ws.
    float* wT  = (float*)d_out;
    float* y   = (float*)((char*)d_out + (size_t)16777216);
    int*   idx = (int*)d_ws;

    hipLaunchKernelGGL(k_transpose_w, dim3(16384), dim3(256), 0, stream, conv_w, wT);
    hipLaunchKernelGGL(k_conv,        dim3(128, 4), dim3(256), 0, stream, x, wT, conv_b, y);
    hipLaunchKernelGGL(k_decode,      dim3(32),    dim3(256), 0, stream, y, lin_w, lin_b, wbias, idx);
    hipLaunchKernelGGL(k_gather,      dim3(BATCH * NOUT * PS), dim3(128), 0, stream, x, idx, out);
}